// Round 9
// baseline (201.081 us; speedup 1.0000x reference)
//
#include <hip/hip_runtime.h>
#include <hip/hip_bf16.h>
#include <math.h>
#include <stdint.h>

#define NB 4
#define NS 2048
#define ND 512
#define NH 8
#define DEP 64

typedef __attribute__((ext_vector_type(8))) short bf16x8;
typedef __attribute__((ext_vector_type(4))) short bf16x4;
typedef __attribute__((ext_vector_type(4))) float f32x4;

#define QSCALE 0.18033688011112042f  // DEPTH^-0.5 * log2(e): softmax in exp2

__device__ __forceinline__ short f2b(float f) {
  unsigned u = __float_as_uint(f);
  u += 0x7FFF + ((u >> 16) & 1);  // RNE
  return (short)(u >> 16);
}
__device__ __forceinline__ unsigned pk2(float a, float b) {
  union { __hip_bfloat162 h; unsigned u; } c;
  c.h = __float22bfloat162_rn(float2{a, b});
  return c.u;
}
// async 16B global->LDS DMA; LDS dest is wave-uniform base + lane*16
__device__ __forceinline__ void dma16(const void* g, void* l) {
  __builtin_amdgcn_global_load_lds(
      (const __attribute__((address_space(1))) void*)g,
      (__attribute__((address_space(3))) void*)l, 16, 0, 0);
}

// ---------------------------------------------------------------------------
// prep: one launch does BOTH input casts and all 4 weight transposes.
// grid (4096, 3): y=0 cast x, y=1 cast y, y=2 (x<256) transpose W0..W3.
// ---------------------------------------------------------------------------
__global__ __launch_bounds__(256) void prep(
    const float* __restrict__ x, const float* __restrict__ y,
    const float* __restrict__ W0, const float* __restrict__ W1,
    const float* __restrict__ W2, const float* __restrict__ W3,
    short* __restrict__ xb, short* __restrict__ yb, short* __restrict__ T0,
    short* __restrict__ T1, short* __restrict__ T2, short* __restrict__ T3) {
  const int t = threadIdx.x;
  if (blockIdx.y < 2) {
    const float* src = blockIdx.y ? y : x;
    short* dst = blockIdx.y ? yb : xb;
    size_t i = ((size_t)blockIdx.x * 256 + t) * 4;
    float4 v = *(const float4*)(src + i);
    bf16x4 o;
    o[0] = f2b(v.x); o[1] = f2b(v.y); o[2] = f2b(v.z); o[3] = f2b(v.w);
    *(bf16x4*)(dst + i) = o;
    return;
  }
  const int bx = blockIdx.x;
  if (bx >= 256) return;
  const int wj = bx >> 6, rem = bx & 63;
  const float* W = wj == 0 ? W0 : wj == 1 ? W1 : wj == 2 ? W2 : W3;
  short* T = wj == 0 ? T0 : wj == 1 ? T1 : wj == 2 ? T2 : T3;
  __shared__ float tile[64][65];
  const int k0 = (rem >> 3) * 64, n0 = (rem & 7) * 64;
#pragma unroll
  for (int i = 0; i < 4; ++i) {
    int r = (t >> 4) + i * 16;
    int c = (t & 15) * 4;
    float4 v = *(const float4*)&W[(size_t)(k0 + r) * ND + n0 + c];
    tile[r][c] = v.x; tile[r][c + 1] = v.y;
    tile[r][c + 2] = v.z; tile[r][c + 3] = v.w;
  }
  __syncthreads();
#pragma unroll
  for (int i = 0; i < 4; ++i) {
    int n = (t >> 4) + i * 16;
    int kc = (t & 15) * 4;
    bf16x4 o;
#pragma unroll
    for (int j = 0; j < 4; ++j) o[j] = f2b(tile[kc + j][n]);
    *(bf16x4*)&T[(size_t)(n0 + n) * ND + k0 + kc] = o;
  }
}

// ---------------------------------------------------------------------------
// Fused QKV GEMM.  grid (8, 64, 2); tile 128 (M) x 64 (N), BK=64.
// z=0: Q = x.Wq^T (bf16 row-major, alpha=QSCALE).
// z=1: K = y.Wk^T (bf16 row-major) AND V^T = (y.Wv^T)^T scattered to
//      Vt[b][h][d][s] -- the y-tile is staged ONCE and its af fragments
//      feed both weight matrices (2x MFMA per staged A byte).
// Single-buffer DMA staging, 2 barriers/iter, XOR-swizzled LDS.
// ---------------------------------------------------------------------------
__global__ __launch_bounds__(256) void qkv_gemm(
    const short* __restrict__ xb, const short* __restrict__ yb,
    const short* __restrict__ Wqt, const short* __restrict__ Wkt,
    const short* __restrict__ Wvt, short* __restrict__ Qb,
    short* __restrict__ Kb, short* __restrict__ Vtb) {
  __shared__ short As[128 * 64];
  __shared__ short B0s[64 * 64];
  __shared__ short B1s[64 * 64];
  const int z = blockIdx.z;
  const short* A = z ? yb : xb;
  const short* Bt0 = z ? Wkt : Wqt;
  const int t = threadIdx.x;
  const int wave = t >> 6, lane = t & 63;
  const int m = lane & 15, quad = lane >> 4;
  const int m0 = blockIdx.y * 128, n0 = blockIdx.x * 64;
  const int mh = (wave >> 1) * 64, nh = (wave & 1) * 32;
  const int r8 = lane >> 3;
  const int c8 = (lane & 7) ^ r8;
  const int mx7 = m & 7;
  f32x4 acc0[4][2], acc1[4][2];
#pragma unroll
  for (int i = 0; i < 4; ++i)
#pragma unroll
    for (int j = 0; j < 2; ++j) {
      acc0[i][j] = (f32x4){0.f, 0.f, 0.f, 0.f};
      acc1[i][j] = (f32x4){0.f, 0.f, 0.f, 0.f};
    }

  for (int k0 = 0; k0 < ND; k0 += 64) {
    __syncthreads();  // prior iteration's fragment readers done
#pragma unroll
    for (int i = 0; i < 4; ++i)
      dma16(A + (size_t)(m0 + i * 32 + wave * 8 + r8) * ND + k0 + c8 * 8,
            As + (i * 256 + wave * 64) * 8);
#pragma unroll
    for (int i = 0; i < 2; ++i)
      dma16(Bt0 + (size_t)(n0 + i * 32 + wave * 8 + r8) * ND + k0 + c8 * 8,
            B0s + (i * 256 + wave * 64) * 8);
    if (z) {
#pragma unroll
      for (int i = 0; i < 2; ++i)
        dma16(Wvt + (size_t)(n0 + i * 32 + wave * 8 + r8) * ND + k0 + c8 * 8,
              B1s + (i * 256 + wave * 64) * 8);
    }
    __syncthreads();  // drains vmcnt: all DMA visible
    bf16x8 af[4][2], bf0[2][2];
#pragma unroll
    for (int mt = 0; mt < 4; ++mt)
#pragma unroll
      for (int kc = 0; kc < 2; ++kc)
        af[mt][kc] = *(const bf16x8*)(As + (mh + mt * 16 + m) * 64 +
                                      ((kc * 4 + quad) ^ mx7) * 8);
#pragma unroll
    for (int nt = 0; nt < 2; ++nt)
#pragma unroll
      for (int kc = 0; kc < 2; ++kc)
        bf0[nt][kc] = *(const bf16x8*)(B0s + (nh + nt * 16 + m) * 64 +
                                       ((kc * 4 + quad) ^ mx7) * 8);
#pragma unroll
    for (int mt = 0; mt < 4; ++mt)
#pragma unroll
      for (int nt = 0; nt < 2; ++nt)
#pragma unroll
        for (int kc = 0; kc < 2; ++kc)
          acc0[mt][nt] = __builtin_amdgcn_mfma_f32_16x16x32_bf16(
              af[mt][kc], bf0[nt][kc], acc0[mt][nt], 0, 0, 0);
    if (z) {
      bf16x8 bf1[2][2];
#pragma unroll
      for (int nt = 0; nt < 2; ++nt)
#pragma unroll
        for (int kc = 0; kc < 2; ++kc)
          bf1[nt][kc] = *(const bf16x8*)(B1s + (nh + nt * 16 + m) * 64 +
                                         ((kc * 4 + quad) ^ mx7) * 8);
#pragma unroll
      for (int mt = 0; mt < 4; ++mt)
#pragma unroll
        for (int nt = 0; nt < 2; ++nt)
#pragma unroll
          for (int kc = 0; kc < 2; ++kc)
            acc1[mt][nt] = __builtin_amdgcn_mfma_f32_16x16x32_bf16(
                af[mt][kc], bf1[nt][kc], acc1[mt][nt], 0, 0, 0);
    }
  }
  // epilogue: acc0 -> row-major bf16 (Q or K)
  short* C0 = z ? Kb : Qb;
  const float alpha0 = z ? 1.0f : QSCALE;
#pragma unroll
  for (int mt = 0; mt < 4; ++mt)
#pragma unroll
    for (int nt = 0; nt < 2; ++nt)
#pragma unroll
      for (int r = 0; r < 4; ++r) {
        int row = m0 + mh + mt * 16 + quad * 4 + r;
        int col = n0 + nh + nt * 16 + m;
        C0[(size_t)row * ND + col] = f2b(acc0[mt][nt][r] * alpha0);
      }
  if (z) {
    // acc1 -> V^T: (token row, channel col) -> Vt[b][h][d][s]
#pragma unroll
    for (int mt = 0; mt < 4; ++mt)
#pragma unroll
      for (int nt = 0; nt < 2; ++nt) {
        int row0 = m0 + mh + mt * 16 + quad * 4;
        int col = n0 + nh + nt * 16 + m;
        int b_ = row0 >> 11, s_ = row0 & (NS - 1);
        int h_ = col >> 6, d_ = col & (DEP - 1);
        uint2 p;
        p.x = pk2(acc1[mt][nt][0], acc1[mt][nt][1]);
        p.y = pk2(acc1[mt][nt][2], acc1[mt][nt][3]);
        *(uint2*)(Vtb + (size_t)((b_ * NH + h_) * DEP + d_) * NS + s_) = p;
      }
  }
}

// ---------------------------------------------------------------------------
// Output GEMM: 128x64 tile, BK=64, double-buffered DMA, swizzled LDS,
// fp32 row-major out.
// ---------------------------------------------------------------------------
__global__ __launch_bounds__(256) void out_gemm(const short* __restrict__ A,
                                                const short* __restrict__ Bt,
                                                float* __restrict__ Cout) {
  __shared__ short As[2][128 * 64];
  __shared__ short Bs[2][64 * 64];
  const int t = threadIdx.x;
  const int wave = t >> 6, lane = t & 63;
  const int m = lane & 15, quad = lane >> 4;
  const int m0 = blockIdx.y * 128, n0 = blockIdx.x * 64;
  const int mh = (wave >> 1) * 64, nh = (wave & 1) * 32;
  const int r8 = lane >> 3;
  const int c8 = (lane & 7) ^ r8;
  const int mx7 = m & 7;
  f32x4 acc[4][2];
#pragma unroll
  for (int i = 0; i < 4; ++i)
#pragma unroll
    for (int j = 0; j < 2; ++j) acc[i][j] = (f32x4){0.f, 0.f, 0.f, 0.f};

#pragma unroll
  for (int i = 0; i < 4; ++i)
    dma16(A + (size_t)(m0 + i * 32 + wave * 8 + r8) * ND + c8 * 8,
          As[0] + (i * 256 + wave * 64) * 8);
#pragma unroll
  for (int i = 0; i < 2; ++i)
    dma16(Bt + (size_t)(n0 + i * 32 + wave * 8 + r8) * ND + c8 * 8,
          Bs[0] + (i * 256 + wave * 64) * 8);

  int buf = 0;
  for (int k0 = 0; k0 < ND; k0 += 64, buf ^= 1) {
    __syncthreads();
    if (k0 + 64 < ND) {
#pragma unroll
      for (int i = 0; i < 4; ++i)
        dma16(A + (size_t)(m0 + i * 32 + wave * 8 + r8) * ND + k0 + 64 + c8 * 8,
              As[buf ^ 1] + (i * 256 + wave * 64) * 8);
#pragma unroll
      for (int i = 0; i < 2; ++i)
        dma16(Bt + (size_t)(n0 + i * 32 + wave * 8 + r8) * ND + k0 + 64 +
                  c8 * 8,
              Bs[buf ^ 1] + (i * 256 + wave * 64) * 8);
    }
    bf16x8 af[4][2], bf[2][2];
#pragma unroll
    for (int mt = 0; mt < 4; ++mt)
#pragma unroll
      for (int kc = 0; kc < 2; ++kc)
        af[mt][kc] = *(const bf16x8*)(As[buf] + (mh + mt * 16 + m) * 64 +
                                      ((kc * 4 + quad) ^ mx7) * 8);
#pragma unroll
    for (int nt = 0; nt < 2; ++nt)
#pragma unroll
      for (int kc = 0; kc < 2; ++kc)
        bf[nt][kc] = *(const bf16x8*)(Bs[buf] + (nh + nt * 16 + m) * 64 +
                                      ((kc * 4 + quad) ^ mx7) * 8);
#pragma unroll
    for (int mt = 0; mt < 4; ++mt)
#pragma unroll
      for (int nt = 0; nt < 2; ++nt)
#pragma unroll
        for (int kc = 0; kc < 2; ++kc)
          acc[mt][nt] = __builtin_amdgcn_mfma_f32_16x16x32_bf16(
              af[mt][kc], bf[nt][kc], acc[mt][nt], 0, 0, 0);
  }
#pragma unroll
  for (int mt = 0; mt < 4; ++mt)
#pragma unroll
    for (int nt = 0; nt < 2; ++nt)
#pragma unroll
      for (int r = 0; r < 4; ++r) {
        int row = m0 + mh + mt * 16 + quad * 4 + r;
        int col = n0 + nh + nt * 16 + m;
        Cout[(size_t)row * ND + col] = acc[mt][nt][r];
      }
}

// ---------------------------------------------------------------------------
// Flash attention, quadrant decomposition.  Block = 64 q x (b,h), 4 waves.
// Wave (kh = wave>>1, qh = wave&1) computes the S^T quadrant
// [32 kv (kh half)] x [32 q (qh half)] and the PARTIAL O^T [64 d][32 q]
// over its kv half.  Pt quadrants are wave-private (rows shared, col-chunks
// disjoint) => no barrier between P write and PV read => ONE barrier/iter
// with double-buffered K/V DMA.  Partial O + l combined via LDS in epilogue.
// Max-free softmax (raw v_exp_f32), log2-domain scores (QSCALE in Q).
// ---------------------------------------------------------------------------
__global__ __launch_bounds__(256) void attn_mfma(const short* __restrict__ Qb,
                                                 const short* __restrict__ Kb,
                                                 const short* __restrict__ Vtb,
                                                 short* __restrict__ Ob) {
  __shared__ short Ks[2][64 * 64];   // [kv][d], swizzled
  __shared__ short Vts[2][64 * 64];  // [d][kv], swizzled
  __shared__ short Pt[64 * 64];      // [q][kv], swizzled, quadrant-private
  const int t = threadIdx.x;
  const int wave = t >> 6, lane = t & 63;
  const int m = lane & 15, quad = lane >> 4;
  const int kh = wave >> 1, qh = wave & 1;
  const int bh = blockIdx.y, b = bh >> 3, h = bh & 7;
  const int q0 = blockIdx.x * 64;
  const size_t rowb = (size_t)b * NS;
  const short* Vtbase = Vtb + (size_t)(bh * DEP) * NS;
  const int r8 = lane >> 3;
  const int c8 = (lane & 7) ^ r8;
  const int mx7 = m & 7;

  // Q fragments (B-operand) for this wave's 32 q columns
  bf16x8 qf[2][2];
#pragma unroll
  for (int nt = 0; nt < 2; ++nt)
#pragma unroll
    for (int kc = 0; kc < 2; ++kc)
      qf[nt][kc] =
          *(const bf16x8*)(Qb + (rowb + q0 + qh * 32 + nt * 16 + m) * ND +
                           h * DEP + kc * 32 + quad * 8);

  float l_[2] = {0.0f, 0.0f};  // per-lane partial row sums (kv half)
  f32x4 Ot[4][2];              // partial O^T [64 d][32 q], C layout
#pragma unroll
  for (int mt = 0; mt < 4; ++mt)
#pragma unroll
    for (int nt = 0; nt < 2; ++nt) Ot[mt][nt] = (f32x4){0.f, 0.f, 0.f, 0.f};

  // prefetch kv-tile 0 into buffer 0
#pragma unroll
  for (int i = 0; i < 2; ++i) {
    int row = i * 32 + wave * 8 + r8;
    dma16(Kb + (rowb + row) * ND + h * DEP + c8 * 8,
          Ks[0] + (i * 256 + wave * 64) * 8);
    dma16(Vtbase + (size_t)row * NS + c8 * 8,
          Vts[0] + (i * 256 + wave * 64) * 8);
  }

  int buf = 0;
  for (int kv0 = 0; kv0 < NS; kv0 += 64, buf ^= 1) {
    __syncthreads();  // drains DMA(buf); all waves past prior iter's reads
    if (kv0 + 64 < NS) {
#pragma unroll
      for (int i = 0; i < 2; ++i) {
        int row = i * 32 + wave * 8 + r8;
        dma16(Kb + (rowb + kv0 + 64 + row) * ND + h * DEP + c8 * 8,
              Ks[buf ^ 1] + (i * 256 + wave * 64) * 8);
        dma16(Vtbase + (size_t)row * NS + kv0 + 64 + c8 * 8,
              Vts[buf ^ 1] + (i * 256 + wave * 64) * 8);
      }
    }

    // S^T quadrant = K(kh half) . Q^T(qh half): 32 kv x 32 q
    f32x4 St[2][2];
#pragma unroll
    for (int mt = 0; mt < 2; ++mt)
#pragma unroll
      for (int nt = 0; nt < 2; ++nt) St[mt][nt] = (f32x4){0.f, 0.f, 0.f, 0.f};
#pragma unroll
    for (int mt = 0; mt < 2; ++mt)
#pragma unroll
      for (int kc = 0; kc < 2; ++kc) {
        bf16x8 kf =
            *(const bf16x8*)(Ks[buf] + (kh * 32 + mt * 16 + m) * 64 +
                             ((kc * 4 + quad) ^ mx7) * 8);
#pragma unroll
        for (int nt = 0; nt < 2; ++nt)
          St[mt][nt] = __builtin_amdgcn_mfma_f32_16x16x32_bf16(
              kf, qf[nt][kc], St[mt][nt], 0, 0, 0);
      }

    // max-free softmax; write quadrant of Pt (wave-private chunks)
#pragma unroll
    for (int nt = 0; nt < 2; ++nt) {
      float rs = 0.0f;
#pragma unroll
      for (int mt = 0; mt < 2; ++mt) {
        float p0 = __builtin_amdgcn_exp2f(St[mt][nt][0]);
        float p1 = __builtin_amdgcn_exp2f(St[mt][nt][1]);
        float p2 = __builtin_amdgcn_exp2f(St[mt][nt][2]);
        float p3 = __builtin_amdgcn_exp2f(St[mt][nt][3]);
        rs += (p0 + p1) + (p2 + p3);
        uint2 pk;
        pk.x = pk2(p0, p1);
        pk.y = pk2(p2, p3);
        *(uint2*)(Pt + (qh * 32 + nt * 16 + m) * 64 +
                  ((kh * 4 + mt * 2 + (quad >> 1)) ^ mx7) * 8 +
                  (quad & 1) * 4) = pk;
      }
      l_[nt] += rs;
    }

    // partial O^T += V^T(all 64 d, kh kv-half) . P^T(quadrant)
#pragma unroll
    for (int nt = 0; nt < 2; ++nt) {
      bf16x8 pf = *(const bf16x8*)(Pt + (qh * 32 + nt * 16 + m) * 64 +
                                   ((kh * 4 + quad) ^ mx7) * 8);
#pragma unroll
      for (int mt = 0; mt < 4; ++mt) {
        bf16x8 vf = *(const bf16x8*)(Vts[buf] + (mt * 16 + m) * 64 +
                                     ((kh * 4 + quad) ^ mx7) * 8);
        Ot[mt][nt] = __builtin_amdgcn_mfma_f32_16x16x32_bf16(vf, pf, Ot[mt][nt],
                                                             0, 0, 0);
      }
    }
  }

  // epilogue: reduce l across quads; combine kv-half partials via LDS
#pragma unroll
  for (int nt = 0; nt < 2; ++nt) {
    l_[nt] += __shfl_xor(l_[nt], 16, 64);
    l_[nt] += __shfl_xor(l_[nt], 32, 64);
  }
  float* obuf = (float*)Ks;   // 16 KB: 2 waves x 64 lanes x 32 floats
  float* lv = (float*)Vts;    // 64 floats
  if (kh == 1) {
    float* dst = obuf + (qh * 64 + lane) * 32;
#pragma unroll
    for (int mt = 0; mt < 4; ++mt)
#pragma unroll
      for (int nt = 0; nt < 2; ++nt)
#pragma unroll
        for (int r = 0; r < 4; ++r) dst[mt * 8 + nt * 4 + r] = Ot[mt][nt][r];
    if (quad == 0) {
      lv[qh * 32 + m] = l_[0];
      lv[qh * 32 + 16 + m] = l_[1];
    }
  }
  __syncthreads();
  if (kh == 0) {
    const float* src = obuf + (qh * 64 + lane) * 32;
    float linv[2];
#pragma unroll
    for (int nt = 0; nt < 2; ++nt)
      linv[nt] = 1.0f / (l_[nt] + lv[qh * 32 + nt * 16 + m]);
#pragma unroll
    for (int nt = 0; nt < 2; ++nt) {
      size_t row = rowb + q0 + qh * 32 + nt * 16 + m;
#pragma unroll
      for (int mt = 0; mt < 4; ++mt) {
        float v0 = (Ot[mt][nt][0] + src[mt * 8 + nt * 4 + 0]) * linv[nt];
        float v1 = (Ot[mt][nt][1] + src[mt * 8 + nt * 4 + 1]) * linv[nt];
        float v2 = (Ot[mt][nt][2] + src[mt * 8 + nt * 4 + 2]) * linv[nt];
        float v3 = (Ot[mt][nt][3] + src[mt * 8 + nt * 4 + 3]) * linv[nt];
        uint2 p;
        p.x = pk2(v0, v1);
        p.y = pk2(v2, v3);
        *(uint2*)(Ob + row * ND + h * DEP + mt * 16 + quad * 4) = p;
      }
    }
  }
}

// ---------------------------------------------------------------------------
extern "C" void kernel_launch(void* const* d_in, const int* in_sizes, int n_in,
                              void* d_out, int out_size, void* d_ws,
                              size_t ws_size, hipStream_t stream) {
  const float* x = (const float*)d_in[0];
  const float* y = (const float*)d_in[1];
  const float* Wq = (const float*)d_in[2];
  const float* Wk = (const float*)d_in[3];
  const float* Wv = (const float*)d_in[4];
  const float* Wo = (const float*)d_in[5];
  float* out = (float*)d_out;

  const size_t mat = (size_t)NB * NS * ND;
  const size_t wsz = (size_t)ND * ND;
  short* xb = (short*)d_ws;
  short* yb = xb + mat;
  short* Wqt = yb + mat;
  short* Wkt = Wqt + wsz;
  short* Wvt = Wkt + wsz;
  short* Wot = Wvt + wsz;
  short* Qb = Wot + wsz;
  short* Kb = Qb + mat;
  short* Vtb = Kb + mat;
  short* attnb = xb;  // reuse: xb dead after QKV GEMM

  prep<<<dim3(mat / 1024, 3), 256, 0, stream>>>(x, y, Wq, Wk, Wv, Wo, xb, yb,
                                                Wqt, Wkt, Wvt, Wot);
  qkv_gemm<<<dim3(ND / 64, (NB * NS) / 128, 2), 256, 0, stream>>>(
      xb, yb, Wqt, Wkt, Wvt, Qb, Kb, Vtb);
  attn_mfma<<<dim3(NS / 64, NB * NH), 256, 0, stream>>>(Qb, Kb, Vtb, attnb);
  out_gemm<<<dim3(ND / 64, (NB * NS) / 128), 256, 0, stream>>>(attnb, Wot,
                                                               out);
}

// Round 11
// 190.163 us; speedup vs baseline: 1.0574x; 1.0574x over previous
//
#include <hip/hip_runtime.h>
#include <hip/hip_bf16.h>
#include <math.h>
#include <stdint.h>

#define NB 4
#define NS 2048
#define ND 512
#define NH 8
#define DEP 64

typedef __attribute__((ext_vector_type(8))) short bf16x8;
typedef __attribute__((ext_vector_type(4))) short bf16x4;
typedef __attribute__((ext_vector_type(4))) float f32x4;
typedef __attribute__((ext_vector_type(16))) float f32x16;

#define QSCALE 0.18033688011112042f  // DEPTH^-0.5 * log2(e): softmax in exp2

__device__ __forceinline__ short f2b(float f) {
  unsigned u = __float_as_uint(f);
  u += 0x7FFF + ((u >> 16) & 1);  // RNE
  return (short)(u >> 16);
}
__device__ __forceinline__ unsigned pk2(float a, float b) {
  union { __hip_bfloat162 h; unsigned u; } c;
  c.h = __float22bfloat162_rn(float2{a, b});
  return c.u;
}
// async 16B global->LDS DMA; LDS dest is wave-uniform base + lane*16
__device__ __forceinline__ void dma16(const void* g, void* l) {
  __builtin_amdgcn_global_load_lds(
      (const __attribute__((address_space(1))) void*)g,
      (__attribute__((address_space(3))) void*)l, 16, 0, 0);
}

// ---------------------------------------------------------------------------
// prep: one launch does BOTH input casts and all 4 weight transposes.
// ---------------------------------------------------------------------------
__global__ __launch_bounds__(256) void prep(
    const float* __restrict__ x, const float* __restrict__ y,
    const float* __restrict__ W0, const float* __restrict__ W1,
    const float* __restrict__ W2, const float* __restrict__ W3,
    short* __restrict__ xb, short* __restrict__ yb, short* __restrict__ T0,
    short* __restrict__ T1, short* __restrict__ T2, short* __restrict__ T3) {
  const int t = threadIdx.x;
  if (blockIdx.y < 2) {
    const float* src = blockIdx.y ? y : x;
    short* dst = blockIdx.y ? yb : xb;
    size_t i = ((size_t)blockIdx.x * 256 + t) * 4;
    float4 v = *(const float4*)(src + i);
    bf16x4 o;
    o[0] = f2b(v.x); o[1] = f2b(v.y); o[2] = f2b(v.z); o[3] = f2b(v.w);
    *(bf16x4*)(dst + i) = o;
    return;
  }
  const int bx = blockIdx.x;
  if (bx >= 256) return;
  const int wj = bx >> 6, rem = bx & 63;
  const float* W = wj == 0 ? W0 : wj == 1 ? W1 : wj == 2 ? W2 : W3;
  short* T = wj == 0 ? T0 : wj == 1 ? T1 : wj == 2 ? T2 : T3;
  __shared__ float tile[64][65];
  const int k0 = (rem >> 3) * 64, n0 = (rem & 7) * 64;
#pragma unroll
  for (int i = 0; i < 4; ++i) {
    int r = (t >> 4) + i * 16;
    int c = (t & 15) * 4;
    float4 v = *(const float4*)&W[(size_t)(k0 + r) * ND + n0 + c];
    tile[r][c] = v.x; tile[r][c + 1] = v.y;
    tile[r][c + 2] = v.z; tile[r][c + 3] = v.w;
  }
  __syncthreads();
#pragma unroll
  for (int i = 0; i < 4; ++i) {
    int n = (t >> 4) + i * 16;
    int kc = (t & 15) * 4;
    bf16x4 o;
#pragma unroll
    for (int j = 0; j < 4; ++j) o[j] = f2b(tile[kc + j][n]);
    *(bf16x4*)&T[(size_t)(n0 + n) * ND + k0 + kc] = o;
  }
}

// ---------------------------------------------------------------------------
// Fused QKV GEMM.  grid (8, 64, 2); tile 128 (M) x 64 (N), BK=64.
// z=0: Q.  z=1: K row-major AND V^T (y-tile staged once, 2x MFMA per A byte).
// ---------------------------------------------------------------------------
__global__ __launch_bounds__(256) void qkv_gemm(
    const short* __restrict__ xb, const short* __restrict__ yb,
    const short* __restrict__ Wqt, const short* __restrict__ Wkt,
    const short* __restrict__ Wvt, short* __restrict__ Qb,
    short* __restrict__ Kb, short* __restrict__ Vtb) {
  __shared__ short As[128 * 64];
  __shared__ short B0s[64 * 64];
  __shared__ short B1s[64 * 64];
  const int z = blockIdx.z;
  const short* A = z ? yb : xb;
  const short* Bt0 = z ? Wkt : Wqt;
  const int t = threadIdx.x;
  const int wave = t >> 6, lane = t & 63;
  const int m = lane & 15, quad = lane >> 4;
  const int m0 = blockIdx.y * 128, n0 = blockIdx.x * 64;
  const int mh = (wave >> 1) * 64, nh = (wave & 1) * 32;
  const int r8 = lane >> 3;
  const int c8 = (lane & 7) ^ r8;
  const int mx7 = m & 7;
  f32x4 acc0[4][2], acc1[4][2];
#pragma unroll
  for (int i = 0; i < 4; ++i)
#pragma unroll
    for (int j = 0; j < 2; ++j) {
      acc0[i][j] = (f32x4){0.f, 0.f, 0.f, 0.f};
      acc1[i][j] = (f32x4){0.f, 0.f, 0.f, 0.f};
    }

  for (int k0 = 0; k0 < ND; k0 += 64) {
    __syncthreads();
#pragma unroll
    for (int i = 0; i < 4; ++i)
      dma16(A + (size_t)(m0 + i * 32 + wave * 8 + r8) * ND + k0 + c8 * 8,
            As + (i * 256 + wave * 64) * 8);
#pragma unroll
    for (int i = 0; i < 2; ++i)
      dma16(Bt0 + (size_t)(n0 + i * 32 + wave * 8 + r8) * ND + k0 + c8 * 8,
            B0s + (i * 256 + wave * 64) * 8);
    if (z) {
#pragma unroll
      for (int i = 0; i < 2; ++i)
        dma16(Wvt + (size_t)(n0 + i * 32 + wave * 8 + r8) * ND + k0 + c8 * 8,
              B1s + (i * 256 + wave * 64) * 8);
    }
    __syncthreads();
    bf16x8 af[4][2], bf0[2][2];
#pragma unroll
    for (int mt = 0; mt < 4; ++mt)
#pragma unroll
      for (int kc = 0; kc < 2; ++kc)
        af[mt][kc] = *(const bf16x8*)(As + (mh + mt * 16 + m) * 64 +
                                      ((kc * 4 + quad) ^ mx7) * 8);
#pragma unroll
    for (int nt = 0; nt < 2; ++nt)
#pragma unroll
      for (int kc = 0; kc < 2; ++kc)
        bf0[nt][kc] = *(const bf16x8*)(B0s + (nh + nt * 16 + m) * 64 +
                                       ((kc * 4 + quad) ^ mx7) * 8);
#pragma unroll
    for (int mt = 0; mt < 4; ++mt)
#pragma unroll
      for (int nt = 0; nt < 2; ++nt)
#pragma unroll
        for (int kc = 0; kc < 2; ++kc)
          acc0[mt][nt] = __builtin_amdgcn_mfma_f32_16x16x32_bf16(
              af[mt][kc], bf0[nt][kc], acc0[mt][nt], 0, 0, 0);
    if (z) {
      bf16x8 bf1[2][2];
#pragma unroll
      for (int nt = 0; nt < 2; ++nt)
#pragma unroll
        for (int kc = 0; kc < 2; ++kc)
          bf1[nt][kc] = *(const bf16x8*)(B1s + (nh + nt * 16 + m) * 64 +
                                         ((kc * 4 + quad) ^ mx7) * 8);
#pragma unroll
      for (int mt = 0; mt < 4; ++mt)
#pragma unroll
        for (int nt = 0; nt < 2; ++nt)
#pragma unroll
          for (int kc = 0; kc < 2; ++kc)
            acc1[mt][nt] = __builtin_amdgcn_mfma_f32_16x16x32_bf16(
                af[mt][kc], bf1[nt][kc], acc1[mt][nt], 0, 0, 0);
    }
  }
  short* C0 = z ? Kb : Qb;
  const float alpha0 = z ? 1.0f : QSCALE;
#pragma unroll
  for (int mt = 0; mt < 4; ++mt)
#pragma unroll
    for (int nt = 0; nt < 2; ++nt)
#pragma unroll
      for (int r = 0; r < 4; ++r) {
        int row = m0 + mh + mt * 16 + quad * 4 + r;
        int col = n0 + nh + nt * 16 + m;
        C0[(size_t)row * ND + col] = f2b(acc0[mt][nt][r] * alpha0);
      }
  if (z) {
#pragma unroll
    for (int mt = 0; mt < 4; ++mt)
#pragma unroll
      for (int nt = 0; nt < 2; ++nt) {
        int row0 = m0 + mh + mt * 16 + quad * 4;
        int col = n0 + nh + nt * 16 + m;
        int b_ = row0 >> 11, s_ = row0 & (NS - 1);
        int h_ = col >> 6, d_ = col & (DEP - 1);
        uint2 p;
        p.x = pk2(acc1[mt][nt][0], acc1[mt][nt][1]);
        p.y = pk2(acc1[mt][nt][2], acc1[mt][nt][3]);
        *(uint2*)(Vtb + (size_t)((b_ * NH + h_) * DEP + d_) * NS + s_) = p;
      }
  }
}

// ---------------------------------------------------------------------------
// Output GEMM: 128x64 tile, BK=64, double-buffered DMA, swizzled LDS.
// ---------------------------------------------------------------------------
__global__ __launch_bounds__(256) void out_gemm(const short* __restrict__ A,
                                                const short* __restrict__ Bt,
                                                float* __restrict__ Cout) {
  __shared__ short As[2][128 * 64];
  __shared__ short Bs[2][64 * 64];
  const int t = threadIdx.x;
  const int wave = t >> 6, lane = t & 63;
  const int m = lane & 15, quad = lane >> 4;
  const int m0 = blockIdx.y * 128, n0 = blockIdx.x * 64;
  const int mh = (wave >> 1) * 64, nh = (wave & 1) * 32;
  const int r8 = lane >> 3;
  const int c8 = (lane & 7) ^ r8;
  const int mx7 = m & 7;
  f32x4 acc[4][2];
#pragma unroll
  for (int i = 0; i < 4; ++i)
#pragma unroll
    for (int j = 0; j < 2; ++j) acc[i][j] = (f32x4){0.f, 0.f, 0.f, 0.f};

#pragma unroll
  for (int i = 0; i < 4; ++i)
    dma16(A + (size_t)(m0 + i * 32 + wave * 8 + r8) * ND + c8 * 8,
          As[0] + (i * 256 + wave * 64) * 8);
#pragma unroll
  for (int i = 0; i < 2; ++i)
    dma16(Bt + (size_t)(n0 + i * 32 + wave * 8 + r8) * ND + c8 * 8,
          Bs[0] + (i * 256 + wave * 64) * 8);

  int buf = 0;
  for (int k0 = 0; k0 < ND; k0 += 64, buf ^= 1) {
    __syncthreads();
    if (k0 + 64 < ND) {
#pragma unroll
      for (int i = 0; i < 4; ++i)
        dma16(A + (size_t)(m0 + i * 32 + wave * 8 + r8) * ND + k0 + 64 + c8 * 8,
              As[buf ^ 1] + (i * 256 + wave * 64) * 8);
#pragma unroll
      for (int i = 0; i < 2; ++i)
        dma16(Bt + (size_t)(n0 + i * 32 + wave * 8 + r8) * ND + k0 + 64 +
                  c8 * 8,
              Bs[buf ^ 1] + (i * 256 + wave * 64) * 8);
    }
    bf16x8 af[4][2], bf[2][2];
#pragma unroll
    for (int mt = 0; mt < 4; ++mt)
#pragma unroll
      for (int kc = 0; kc < 2; ++kc)
        af[mt][kc] = *(const bf16x8*)(As[buf] + (mh + mt * 16 + m) * 64 +
                                      ((kc * 4 + quad) ^ mx7) * 8);
#pragma unroll
    for (int nt = 0; nt < 2; ++nt)
#pragma unroll
      for (int kc = 0; kc < 2; ++kc)
        bf[nt][kc] = *(const bf16x8*)(Bs[buf] + (nh + nt * 16 + m) * 64 +
                                      ((kc * 4 + quad) ^ mx7) * 8);
#pragma unroll
    for (int mt = 0; mt < 4; ++mt)
#pragma unroll
      for (int nt = 0; nt < 2; ++nt)
#pragma unroll
        for (int kc = 0; kc < 2; ++kc)
          acc[mt][nt] = __builtin_amdgcn_mfma_f32_16x16x32_bf16(
              af[mt][kc], bf[nt][kc], acc[mt][nt], 0, 0, 0);
  }
#pragma unroll
  for (int mt = 0; mt < 4; ++mt)
#pragma unroll
    for (int nt = 0; nt < 2; ++nt)
#pragma unroll
      for (int r = 0; r < 4; ++r) {
        int row = m0 + mh + mt * 16 + quad * 4 + r;
        int col = n0 + nh + nt * 16 + m;
        Cout[(size_t)row * ND + col] = acc[mt][nt][r];
      }
}

// ---------------------------------------------------------------------------
// Flash attention on 32x32x16 MFMA (2x MACs per LDS read vs 16x16x32).
// Block = 64 q x (b,h), 4 waves; wave (kh,qh) computes S^T quadrant
// [32 kv (kh half) x 32 q (qh half)] as ONE 32x32 C-tile, and partial
// O^T [64 d x 32 q] over its kv half as two 32x32 tiles.
// C layout (verified): col = lane&31, row = (reg&3) + 8*(reg>>2) + 4*(lane>>5).
// Swizzle key = (row ^ (row>>3)) & 7 computed from the ABSOLUTE LDS row
// (round-10 bug: used tile-local row; upper-half rows need ^4).
// Pt quadrants wave-private -> 1 barrier/iter with double-buffered DMA.
// Max-free softmax (raw v_exp_f32); cross-kh combine via LDS epilogue.
// ---------------------------------------------------------------------------
__global__ __launch_bounds__(256) void attn_mfma(const short* __restrict__ Qb,
                                                 const short* __restrict__ Kb,
                                                 const short* __restrict__ Vtb,
                                                 short* __restrict__ Ob) {
  __shared__ short Ks[2][64 * 64];   // [kv][d], swizzled
  __shared__ short Vts[2][64 * 64];  // [d][kv], swizzled
  __shared__ short Pt[64 * 64];      // [q][kv], swizzled, quadrant-private
  const int t = threadIdx.x;
  const int wave = t >> 6, lane = t & 63;
  const int n32 = lane & 31, l5 = lane >> 5;
  const int kh = wave >> 1, qh = wave & 1;
  const int bh = blockIdx.y, b = bh >> 3, h = bh & 7;
  const int q0 = blockIdx.x * 64;
  const size_t rowb = (size_t)b * NS;
  const short* Vtbase = Vtb + (size_t)(bh * DEP) * NS;
  const int r8 = lane >> 3;
  const int qrow = qh * 32 + n32;            // local q row 0..63
  const int swf = (n32 ^ (n32 >> 3)) & 7;    // key for LDS rows 0..31 (+n32)
  const int swk = swf ^ (kh << 2);           // key for K rows kh*32+n32
  const int swq = (qrow ^ (qrow >> 3)) & 7;  // key for Pt rows

  // Q fragments (B-operand, 4 k-chunks of 16), register-resident
  bf16x8 qf[4];
#pragma unroll
  for (int kc = 0; kc < 4; ++kc)
    qf[kc] = *(const bf16x8*)(Qb + (rowb + q0 + qrow) * ND + h * DEP +
                              kc * 16 + l5 * 8);

  float l_ = 0.0f;
  f32x16 Ot[2];
#pragma unroll
  for (int mt = 0; mt < 2; ++mt)
#pragma unroll
    for (int r = 0; r < 16; ++r) Ot[mt][r] = 0.0f;

  // prefetch kv-tile 0 into buffer 0 (swizzle key = staging-row based)
#pragma unroll
  for (int i = 0; i < 2; ++i) {
    int c8 = (lane & 7) ^ (r8 ^ ((i * 4 + wave) & 7));
    int row = i * 32 + wave * 8 + r8;
    dma16(Kb + (rowb + row) * ND + h * DEP + c8 * 8,
          Ks[0] + (i * 256 + wave * 64) * 8);
    dma16(Vtbase + (size_t)row * NS + c8 * 8,
          Vts[0] + (i * 256 + wave * 64) * 8);
  }

  int buf = 0;
  for (int kv0 = 0; kv0 < NS; kv0 += 64, buf ^= 1) {
    __syncthreads();  // drains DMA(buf); all waves past prior iter's reads
    if (kv0 + 64 < NS) {
#pragma unroll
      for (int i = 0; i < 2; ++i) {
        int c8 = (lane & 7) ^ (r8 ^ ((i * 4 + wave) & 7));
        int row = i * 32 + wave * 8 + r8;
        dma16(Kb + (rowb + kv0 + 64 + row) * ND + h * DEP + c8 * 8,
              Ks[buf ^ 1] + (i * 256 + wave * 64) * 8);
        dma16(Vtbase + (size_t)row * NS + kv0 + 64 + c8 * 8,
              Vts[buf ^ 1] + (i * 256 + wave * 64) * 8);
      }
    }

    // S^T quadrant = K(kh half) . Q^T(qh half): one 32x32 tile, K=64
    f32x16 St;
#pragma unroll
    for (int r = 0; r < 16; ++r) St[r] = 0.0f;
#pragma unroll
    for (int kc = 0; kc < 4; ++kc) {
      bf16x8 kf = *(const bf16x8*)(Ks[buf] + (kh * 32 + n32) * 64 +
                                   ((kc * 2 + l5) ^ swk) * 8);
      St = __builtin_amdgcn_mfma_f32_32x32x16_bf16(kf, qf[kc], St, 0, 0, 0);
    }

    // max-free softmax: 16 scores/lane, all for q col qrow;
    // kv(reg) = kh*32 + (reg&3) + 8*(reg>>2) + 4*l5
    float p[16];
    float rs = 0.0f;
#pragma unroll
    for (int r = 0; r < 16; ++r) {
      p[r] = __builtin_amdgcn_exp2f(St[r]);
      rs += p[r];
    }
    l_ += rs;
#pragma unroll
    for (int r4 = 0; r4 < 4; ++r4) {
      uint2 pk;
      pk.x = pk2(p[r4 * 4 + 0], p[r4 * 4 + 1]);
      pk.y = pk2(p[r4 * 4 + 2], p[r4 * 4 + 3]);
      *(uint2*)(Pt + qrow * 64 + ((kh * 4 + r4) ^ swq) * 8 + l5 * 4) = pk;
    }

    // partial O^T += V^T(kh kv-half) . P^T(quadrant): 2 d-tiles x 2 k-chunks
#pragma unroll
    for (int kc = 0; kc < 2; ++kc) {
      bf16x8 pf = *(const bf16x8*)(Pt + qrow * 64 +
                                   ((kh * 4 + kc * 2 + l5) ^ swq) * 8);
#pragma unroll
      for (int mt = 0; mt < 2; ++mt) {
        bf16x8 vf = *(const bf16x8*)(Vts[buf] + (mt * 32 + n32) * 64 +
                                     ((kh * 4 + kc * 2 + l5) ^ swf ^
                                      (mt << 2)) * 8);
        Ot[mt] =
            __builtin_amdgcn_mfma_f32_32x32x16_bf16(vf, pf, Ot[mt], 0, 0, 0);
      }
    }
  }

  // epilogue: combine l5 halves, then kv-half partials across kh waves
  l_ += __shfl_xor(l_, 32, 64);
  __syncthreads();  // all waves done reading Ks/Vts before reuse as buffers
  float* obuf = (float*)Ks;  // 16 KB: 128 lanes x 32 floats
  float* lv = (float*)Vts;   // 128 floats
  if (kh == 1) {
    float* dst = obuf + (qh * 64 + lane) * 32;
#pragma unroll
    for (int mt = 0; mt < 2; ++mt)
#pragma unroll
      for (int r = 0; r < 16; ++r) dst[mt * 16 + r] = Ot[mt][r];
    lv[qh * 64 + lane] = l_;
  }
  __syncthreads();
  if (kh == 0) {
    const float* src = obuf + (qh * 64 + lane) * 32;
    float linv = 1.0f / (l_ + lv[qh * 64 + lane]);
    size_t grow = rowb + q0 + qrow;
#pragma unroll
    for (int mt = 0; mt < 2; ++mt)
#pragma unroll
      for (int r4 = 0; r4 < 4; ++r4) {
        int d = mt * 32 + 8 * r4 + 4 * l5;
        float v0 = (Ot[mt][r4 * 4 + 0] + src[mt * 16 + r4 * 4 + 0]) * linv;
        float v1 = (Ot[mt][r4 * 4 + 1] + src[mt * 16 + r4 * 4 + 1]) * linv;
        float v2 = (Ot[mt][r4 * 4 + 2] + src[mt * 16 + r4 * 4 + 2]) * linv;
        float v3 = (Ot[mt][r4 * 4 + 3] + src[mt * 16 + r4 * 4 + 3]) * linv;
        uint2 o;
        o.x = pk2(v0, v1);
        o.y = pk2(v2, v3);
        *(uint2*)(Ob + grow * ND + h * DEP + d) = o;
      }
  }
}

// ---------------------------------------------------------------------------
extern "C" void kernel_launch(void* const* d_in, const int* in_sizes, int n_in,
                              void* d_out, int out_size, void* d_ws,
                              size_t ws_size, hipStream_t stream) {
  const float* x = (const float*)d_in[0];
  const float* y = (const float*)d_in[1];
  const float* Wq = (const float*)d_in[2];
  const float* Wk = (const float*)d_in[3];
  const float* Wv = (const float*)d_in[4];
  const float* Wo = (const float*)d_in[5];
  float* out = (float*)d_out;

  const size_t mat = (size_t)NB * NS * ND;
  const size_t wsz = (size_t)ND * ND;
  short* xb = (short*)d_ws;
  short* yb = xb + mat;
  short* Wqt = yb + mat;
  short* Wkt = Wqt + wsz;
  short* Wvt = Wkt + wsz;
  short* Wot = Wvt + wsz;
  short* Qb = Wot + wsz;
  short* Kb = Qb + mat;
  short* Vtb = Kb + mat;
  short* attnb = xb;  // reuse: xb dead after QKV GEMM

  prep<<<dim3(mat / 1024, 3), 256, 0, stream>>>(x, y, Wq, Wk, Wv, Wo, xb, yb,
                                                Wqt, Wkt, Wvt, Wot);
  qkv_gemm<<<dim3(ND / 64, (NB * NS) / 128, 2), 256, 0, stream>>>(
      xb, yb, Wqt, Wkt, Wvt, Qb, Kb, Vtb);
  attn_mfma<<<dim3(NS / 64, NB * NH), 256, 0, stream>>>(Qb, Kb, Vtb, attnb);
  out_gemm<<<dim3(ND / 64, (NB * NS) / 128), 256, 0, stream>>>(attnb, Wot,
                                                               out);
}